// Round 3
// baseline (697.874 us; speedup 1.0000x reference)
//
#include <hip/hip_runtime.h>
#include <stdint.h>

#define T_SEQ 2048
#define D_DIM 512
#define NEXP 8

typedef short bf16x8 __attribute__((ext_vector_type(8)));
typedef float floatx4 __attribute__((ext_vector_type(4)));

__device__ __forceinline__ unsigned short f2bf(float f) {
  union { float f; unsigned u; } v; v.f = f;
  return (unsigned short)((v.u + 0x7fffu + ((v.u >> 16) & 1u)) >> 16);
}

// ---------- prepass 1: K fp32 -> bf16, T2 XOR-swizzle baked into global layout ----------
// K_ws row r (= bh*2048 + k) is 1024B; element d lives at byte (2d) ^ ((k&7)<<4).
__global__ __launch_bounds__(256) void prep_k(const float* __restrict__ K,
                                              unsigned short* __restrict__ kws) {
  int idx = blockIdx.x * 256 + threadIdx.x;   // 16*2048*64 threads total
  int r = idx >> 6;                            // row = bh*2048 + k
  int c = idx & 63;                            // 8-element chunk along d
  const float4* src = (const float4*)(K + ((long)r << 9) + (c << 3));
  float4 a = src[0], b = src[1];
  bf16x8 v;
  v[0]=f2bf(a.x); v[1]=f2bf(a.y); v[2]=f2bf(a.z); v[3]=f2bf(a.w);
  v[4]=f2bf(b.x); v[5]=f2bf(b.y); v[6]=f2bf(b.z); v[7]=f2bf(b.w);
  int pos = (c ^ (r & 7)) << 4;               // swizzled 16B slot within the 1KB row
  *(bf16x8*)((char*)kws + ((long)r << 10) + pos) = v;
}

// ---------- prepass 2: V fp32 -> V^T bf16 [bh][d][k], swizzle baked ----------
// VT row (bh*512+d) is 4096B; element k at byte ((k>>5)<<6) + (((k&31)<<1) ^ (swz4(d)<<4)),
// swz4(d) = (d ^ (d>>2)) & 3  (keeps 16B alignment, spreads the 4 columns of a 64B slice).
__global__ __launch_bounds__(256) void prep_vt(const float* __restrict__ V,
                                               unsigned short* __restrict__ vt) {
  __shared__ unsigned short tile[64][72];      // [k][d] padded
  int bid = blockIdx.x;                        // 16 * 32 * 8 = 4096 blocks
  int bh = bid >> 8;
  int kt = (bid >> 3) & 31;
  int dt = bid & 7;
  int k0 = kt << 6, d0 = dt << 6;
  int tid = threadIdx.x;
  {
    int kl = tid >> 2, dc = (tid & 3) << 4;
    const float4* src = (const float4*)(V + ((long)(bh * T_SEQ + k0 + kl) << 9) + d0 + dc);
#pragma unroll
    for (int i = 0; i < 4; ++i) {
      float4 a = src[i];
      tile[kl][dc + 4*i + 0] = f2bf(a.x);
      tile[kl][dc + 4*i + 1] = f2bf(a.y);
      tile[kl][dc + 4*i + 2] = f2bf(a.z);
      tile[kl][dc + 4*i + 3] = f2bf(a.w);
    }
  }
  __syncthreads();
  {
    int dl = tid >> 2, kc = (tid & 3) << 4;
    int d = d0 + dl;
    int swz = ((d ^ (d >> 2)) & 3) << 4;
    long rowbase = (long)(bh * 512 + d) << 12;
#pragma unroll
    for (int m = 0; m < 2; ++m) {
      bf16x8 v;
#pragma unroll
      for (int j = 0; j < 8; ++j) v[j] = tile[kc + 8*m + j][dl];
      int ks = k0 + kc + 8*m;
      int pos = ((ks >> 5) << 6) + ((((ks & 31) << 1)) ^ swz);
      *(bf16x8*)((char*)vt + rowbase + pos) = v;
    }
  }
}

// ---------- main flash-attention kernel ----------
// grid 256: bid&15 = head (XCD-local heads), bid>>4 = q-tile. 8 waves x 16 q-rows.
// LDS: [0,32KB) K-tile 32x1024B ; [32KB,64KB) VT-tile 512x64B ; P bounce aliases K rows 0..7.
__global__ __launch_bounds__(512, 2) void attn_main(
    const float* __restrict__ Q, const float* __restrict__ route,
    const int* __restrict__ mask, const unsigned short* __restrict__ kws,
    const unsigned short* __restrict__ vtw, float* __restrict__ out) {
  __shared__ __align__(16) char lds[65536];
  const int tid = threadIdx.x;
  const int wq = tid >> 6;
  const int lane = tid & 63;
  const int lq = lane & 15;
  const int g = lane >> 4;
  const int bh = blockIdx.x & 15;
  const int qb = blockIdx.x >> 4;
  const int qw = qb * 128 + wq * 16;           // wave's first q row
  const int b = bh >> 3;

  float g8[NEXP];
#pragma unroll
  for (int e = 0; e < NEXP; ++e) g8[e] = route[b * NEXP + e];

  // Q fragments: lane holds row qw+lq, d = 32t + 8g + i ; gate*0.125 folded in.
  // e = (32t+8g)>>6 is uniform per t (= t>>1) since 8g<=24 never crosses a 64 boundary.
  bf16x8 qa[16];
  {
    const float* qrow = Q + ((long)(bh * T_SEQ + qw + lq) << 9) + g * 8;
#pragma unroll
    for (int t = 0; t < 16; ++t) {
      const float4* p = (const float4*)(qrow + t * 32);
      float4 a = p[0], c = p[1];
      float sc = g8[t >> 1] * 0.125f;
      qa[t][0]=f2bf(a.x*sc); qa[t][1]=f2bf(a.y*sc); qa[t][2]=f2bf(a.z*sc); qa[t][3]=f2bf(a.w*sc);
      qa[t][4]=f2bf(c.x*sc); qa[t][5]=f2bf(c.y*sc); qa[t][6]=f2bf(c.z*sc); qa[t][7]=f2bf(c.w*sc);
    }
  }

  floatx4 acc[32];                              // O accumulator: 16 rows x 512 d per wave
#pragma unroll
  for (int n = 0; n < 32; ++n) acc[n] = 0.f;
  float mrun[4] = {-3e38f, -3e38f, -3e38f, -3e38f};
  float lrun[4] = {0.f, 0.f, 0.f, 0.f};

  const char* kbase = (const char*)kws + ((long)bh << 21);   // bh * 2048 * 1024
  const char* vbase = (const char*)vtw + ((long)bh << 21);   // bh * 512 * 4096
  const int swzK = (lq & 7) << 4;
  const int swzA = ((lq ^ (lq >> 2)) & 3) << 4;

  for (int kt = 0; kt < T_SEQ / 32; ++kt) {
    const int k0 = kt * 32;
    __syncthreads();                            // previous tile's reads done
    // ---- stage K[32][512] (linear: swizzle pre-baked) ----
#pragma unroll
    for (int r = 0; r < 4; ++r) {
      int row = 4 * wq + r;
      bf16x8 v = *(const bf16x8*)(kbase + ((long)(k0 + row) << 10) + lane * 16);
      *(bf16x8*)(lds + row * 1024 + lane * 16) = v;
    }
    // ---- stage VT[512][32] (linear) ----
#pragma unroll
    for (int r = 0; r < 4; ++r) {
      int drow = 64 * wq + 16 * r + (lane >> 2);
      bf16x8 v = *(const bf16x8*)(vbase + ((long)drow << 12) + k0 * 2 + (lane & 3) * 16);
      *(bf16x8*)(lds + 32768 + drow * 64 + (lane & 3) * 16) = v;
    }
    __syncthreads();                            // tiles staged
    // mask prefetch (latency hidden under the 32 MFMAs below)
    int mv0[4], mv1[4];
#pragma unroll
    for (int j = 0; j < 4; ++j) {
      long mr = (long)(qw + 4 * g + j) * T_SEQ + k0;
      mv0[j] = mask[mr + lq];
      mv1[j] = mask[mr + 16 + lq];
    }
    // ---- S = Q' K^T (two 16-col tiles) ----
    floatx4 s0 = 0.f, s1 = 0.f;
#pragma unroll
    for (int t = 0; t < 16; ++t) {
      int off = (t * 64 + g * 16) ^ swzK;
      bf16x8 kf0 = *(const bf16x8*)(lds + lq * 1024 + off);
      bf16x8 kf1 = *(const bf16x8*)(lds + (16 + lq) * 1024 + off);
      s0 = __builtin_amdgcn_mfma_f32_16x16x32_bf16(qa[t], kf0, s0, 0, 0, 0);
      s1 = __builtin_amdgcn_mfma_f32_16x16x32_bf16(qa[t], kf1, s1, 0, 0, 0);
    }
    __syncthreads();                            // all K reads done -> P region writable
    // ---- online softmax (fp32), masked = -3e38 (self-correcting state) ----
    float al[4];
    int grow = 0;
#pragma unroll
    for (int j = 0; j < 4; ++j) {
      if (mv0[j]) s0[j] = -3e38f;
      if (mv1[j]) s1[j] = -3e38f;
      float tm = fmaxf(s0[j], s1[j]);
      tm = fmaxf(tm, __shfl_xor(tm, 1));
      tm = fmaxf(tm, __shfl_xor(tm, 2));
      tm = fmaxf(tm, __shfl_xor(tm, 4));
      tm = fmaxf(tm, __shfl_xor(tm, 8));
      float mn = fmaxf(mrun[j], tm);
      al[j] = __expf(mrun[j] - mn);
      grow |= (mn > mrun[j]) ? 1 : 0;
      mrun[j] = mn;
      float p0 = __expf(s0[j] - mn);
      float p1 = __expf(s1[j] - mn);
      s0[j] = p0; s1[j] = p1;
      float rs = p0 + p1;
      rs += __shfl_xor(rs, 1);
      rs += __shfl_xor(rs, 2);
      rs += __shfl_xor(rs, 4);
      rs += __shfl_xor(rs, 8);
      lrun[j] = lrun[j] * al[j] + rs;
    }
    if (__any(grow)) {                          // defer-rescale: skip when max unchanged
#pragma unroll
      for (int n = 0; n < 32; ++n) {
#pragma unroll
        for (int j = 0; j < 4; ++j) acc[n][j] *= al[j];
      }
    }
    // ---- P -> LDS bounce (wave-private 1KB, aliases K rows 0..7) ----
    char* pbase = lds + wq * 1024;
#pragma unroll
    for (int j = 0; j < 4; ++j) {
      int q = 4 * g + j;
      int swzP = ((q ^ (q >> 2)) & 3) << 4;
      *(unsigned short*)(pbase + q * 64 + ((2 * lq) ^ swzP))      = f2bf(s0[j]);
      *(unsigned short*)(pbase + q * 64 + ((32 + 2 * lq) ^ swzP)) = f2bf(s1[j]);
    }
    // ---- O += P V ----
    bf16x8 pa = *(const bf16x8*)(pbase + lq * 64 + ((16 * g) ^ swzA));
#pragma unroll
    for (int n = 0; n < 32; ++n) {
      int d = 16 * n + lq;
      int swzV = ((d ^ (d >> 2)) & 3) << 4;
      bf16x8 vb = *(const bf16x8*)(lds + 32768 + d * 64 + ((16 * g) ^ swzV));
      acc[n] = __builtin_amdgcn_mfma_f32_16x16x32_bf16(pa, vb, acc[n], 0, 0, 0);
    }
  }
  // ---- epilogue: out = acc / l * gate ----
  float rl[4];
#pragma unroll
  for (int j = 0; j < 4; ++j) rl[j] = 1.0f / lrun[j];
#pragma unroll
  for (int n = 0; n < 32; ++n) {
    int d = 16 * n + lq;
    float gg = g8[n >> 2];                      // e = (16n+lq)>>6 = n>>2
    float* op = out + ((long)(bh * T_SEQ + qw + 4 * g) << 9) + d;
#pragma unroll
    for (int j = 0; j < 4; ++j) op[(long)j << 9] = acc[n][j] * rl[j] * gg;
  }
}

extern "C" void kernel_launch(void* const* d_in, const int* in_sizes, int n_in,
                              void* d_out, int out_size, void* d_ws, size_t ws_size,
                              hipStream_t stream) {
  (void)in_sizes; (void)n_in; (void)out_size; (void)ws_size;
  const float* Q     = (const float*)d_in[0];
  const float* K     = (const float*)d_in[1];
  const float* V     = (const float*)d_in[2];
  const float* route = (const float*)d_in[3];
  const int*   mask  = (const int*)d_in[5];   // d_in[4] = ids, unused by reference
  float* out = (float*)d_out;
  unsigned short* kws = (unsigned short*)d_ws;                       // 32 MiB
  unsigned short* vtw = (unsigned short*)((char*)d_ws + 33554432);   // 32 MiB
  prep_k  <<<8192, 256, 0, stream>>>(K, kws);
  prep_vt <<<4096, 256, 0, stream>>>(V, vtw);
  attn_main<<<256, 512, 0, stream>>>(Q, route, mask, kws, vtw, out);
}

// Round 5
// 633.316 us; speedup vs baseline: 1.1019x; 1.1019x over previous
//
#include <hip/hip_runtime.h>
#include <stdint.h>

#define T_SEQ 2048
#define D_DIM 512
#define NEXP 8

typedef short bf16x8 __attribute__((ext_vector_type(8)));
typedef float floatx4 __attribute__((ext_vector_type(4)));

__device__ __forceinline__ unsigned short f2bf(float f) {
  union { float f; unsigned u; } v; v.f = f;
  return (unsigned short)((v.u + 0x7fffu + ((v.u >> 16) & 1u)) >> 16);
}

// async global->LDS, 16B per lane. ldst must be wave-uniform base (HW adds lane*16).
__device__ __forceinline__ void gll16(const void* gsrc, void* ldst) {
  __builtin_amdgcn_global_load_lds(
      (const __attribute__((address_space(1))) unsigned int*)gsrc,
      (__attribute__((address_space(3))) unsigned int*)ldst, 16, 0, 0);
}

// ---------- prepass 1: K fp32 -> bf16, XOR-swizzle baked into global layout ----------
__global__ __launch_bounds__(256) void prep_k(const float* __restrict__ K,
                                              unsigned short* __restrict__ kws) {
  int idx = blockIdx.x * 256 + threadIdx.x;
  int r = idx >> 6;
  int c = idx & 63;
  const float4* src = (const float4*)(K + ((long)r << 9) + (c << 3));
  float4 a = src[0], b = src[1];
  bf16x8 v;
  v[0]=f2bf(a.x); v[1]=f2bf(a.y); v[2]=f2bf(a.z); v[3]=f2bf(a.w);
  v[4]=f2bf(b.x); v[5]=f2bf(b.y); v[6]=f2bf(b.z); v[7]=f2bf(b.w);
  int pos = (c ^ (r & 7)) << 4;
  *(bf16x8*)((char*)kws + ((long)r << 10) + pos) = v;
}

// ---------- prepass 2: V fp32 -> V^T bf16 [bh][d][k], swizzle baked ----------
__global__ __launch_bounds__(256) void prep_vt(const float* __restrict__ V,
                                               unsigned short* __restrict__ vt) {
  __shared__ unsigned short tile[64][72];
  int bid = blockIdx.x;
  int bh = bid >> 8;
  int kt = (bid >> 3) & 31;
  int dt = bid & 7;
  int k0 = kt << 6, d0 = dt << 6;
  int tid = threadIdx.x;
  {
    int kl = tid >> 2, dc = (tid & 3) << 4;
    const float4* src = (const float4*)(V + ((long)(bh * T_SEQ + k0 + kl) << 9) + d0 + dc);
#pragma unroll
    for (int i = 0; i < 4; ++i) {
      float4 a = src[i];
      tile[kl][dc + 4*i + 0] = f2bf(a.x);
      tile[kl][dc + 4*i + 1] = f2bf(a.y);
      tile[kl][dc + 4*i + 2] = f2bf(a.z);
      tile[kl][dc + 4*i + 3] = f2bf(a.w);
    }
  }
  __syncthreads();
  {
    int dl = tid >> 2, kc = (tid & 3) << 4;
    int d = d0 + dl;
    int swz = ((d ^ (d >> 2)) & 3) << 4;
    long rowbase = (long)(bh * 512 + d) << 12;
#pragma unroll
    for (int m = 0; m < 2; ++m) {
      bf16x8 v;
#pragma unroll
      for (int j = 0; j < 8; ++j) v[j] = tile[kc + 8*m + j][dl];
      int ks = k0 + kc + 8*m;
      int pos = ((ks >> 5) << 6) + ((((ks & 31) << 1)) ^ swz);
      *(bf16x8*)((char*)vt + rowbase + pos) = v;
    }
  }
}

// ---------- main flash-attention kernel ----------
// grid 256: bid&15 = head, bid>>4 = q-tile. 8 waves x 16 q-rows.
// LDS: double-buffered {K 32KB + VT 32KB} at 0/65536; P-bounce (stride 80) at 131072
//      (8 waves x 1280B = 10240B -> total 141312B; 139264 was the round-4 OOB bug).
__global__ __launch_bounds__(512, 2) void attn_main(
    const float* __restrict__ Q, const float* __restrict__ route,
    const int* __restrict__ mask, const unsigned short* __restrict__ kws,
    const unsigned short* __restrict__ vtw, float* __restrict__ out) {
  __shared__ __align__(16) char lds[141312];
  const int tid = threadIdx.x;
  const int wq = tid >> 6;
  const int lane = tid & 63;
  const int lq = lane & 15;
  const int g = lane >> 4;
  const int bh = blockIdx.x & 15;
  const int qb = blockIdx.x >> 4;
  const int qw = qb * 128 + wq * 16;
  const int b = bh >> 3;

  float g8[NEXP];
#pragma unroll
  for (int e = 0; e < NEXP; ++e) g8[e] = route[b * NEXP + e];

  // Q fragments: lane holds row qw+lq, d = 32t + 8g + i ; gate*0.125 folded in.
  bf16x8 qa[16];
  {
    const float* qrow = Q + ((long)(bh * T_SEQ + qw + lq) << 9) + g * 8;
#pragma unroll
    for (int t = 0; t < 16; ++t) {
      const float4* p = (const float4*)(qrow + t * 32);
      float4 a = p[0], c = p[1];
      float sc = g8[t >> 1] * 0.125f;
      qa[t][0]=f2bf(a.x*sc); qa[t][1]=f2bf(a.y*sc); qa[t][2]=f2bf(a.z*sc); qa[t][3]=f2bf(a.w*sc);
      qa[t][4]=f2bf(c.x*sc); qa[t][5]=f2bf(c.y*sc); qa[t][6]=f2bf(c.z*sc); qa[t][7]=f2bf(c.w*sc);
    }
  }

  floatx4 acc[32];
#pragma unroll
  for (int n = 0; n < 32; ++n) acc[n] = 0.f;
  float mrun[4] = {-3e38f, -3e38f, -3e38f, -3e38f};
  float lrun[4] = {0.f, 0.f, 0.f, 0.f};

  const char* kbase = (const char*)kws + ((long)bh << 21);
  const char* vbase = (const char*)vtw + ((long)bh << 21);
  const int swzK = (lq & 7) << 4;
  const int swzA = ((lq ^ (lq >> 2)) & 3) << 4;
  char* pbase = lds + 131072 + wq * 1280;      // 16 rows x 80B per wave

  // ---- stage helper: 8 x global_load_lds (4 K rows, 4 VT row-groups) ----
#define STAGE(buf, K0)                                                          \
  {                                                                             \
    char* kb_ = lds + (buf) * 65536;                                            \
    char* vb_ = kb_ + 32768;                                                    \
    _Pragma("unroll")                                                           \
    for (int r = 0; r < 4; ++r) {                                               \
      int row = 4 * wq + r;                                                     \
      gll16(kbase + ((long)((K0) + row) << 10) + lane * 16, kb_ + row * 1024);  \
    }                                                                           \
    _Pragma("unroll")                                                           \
    for (int r = 0; r < 4; ++r) {                                               \
      int dr0 = 64 * wq + 16 * r;                                               \
      gll16(vbase + ((long)(dr0 + (lane >> 2)) << 12) + (K0) * 2 + (lane & 3) * 16, \
            vb_ + dr0 * 64);                                                    \
    }                                                                           \
  }

  // prologue: stage tile 0 into buf 0
  STAGE(0, 0)
  asm volatile("s_waitcnt vmcnt(0)" ::: "memory");
  __syncthreads();

  for (int kt = 0; kt < T_SEQ / 32; ++kt) {
    const int cur = kt & 1;
    const int k0 = kt * 32;
    char* kb = lds + cur * 65536;
    char* vb = kb + 32768;

    // issue next tile's stage early: latency hides under QK+SM+PV
    if (kt + 1 < T_SEQ / 32) {
      STAGE(cur ^ 1, k0 + 32)
    }

    // mask prefetch
    int mv0[4], mv1[4];
#pragma unroll
    for (int j = 0; j < 4; ++j) {
      long mr = (long)(qw + 4 * g + j) * T_SEQ + k0;
      mv0[j] = mask[mr + lq];
      mv1[j] = mask[mr + 16 + lq];
    }

    // ---- S = Q' K^T ----
    floatx4 s0 = 0.f, s1 = 0.f;
#pragma unroll
    for (int t = 0; t < 16; ++t) {
      int off = (t * 64 + g * 16) ^ swzK;
      bf16x8 kf0 = *(const bf16x8*)(kb + lq * 1024 + off);
      bf16x8 kf1 = *(const bf16x8*)(kb + (16 + lq) * 1024 + off);
      s0 = __builtin_amdgcn_mfma_f32_16x16x32_bf16(qa[t], kf0, s0, 0, 0, 0);
      s1 = __builtin_amdgcn_mfma_f32_16x16x32_bf16(qa[t], kf1, s1, 0, 0, 0);
    }

    // ---- online softmax, T13 defer-max (THR=8) ----
    float tmv[4];
    int grow = 0;
#pragma unroll
    for (int j = 0; j < 4; ++j) {
      if (mv0[j]) s0[j] = -3e38f;
      if (mv1[j]) s1[j] = -3e38f;
      float tm = fmaxf(s0[j], s1[j]);
      tm = fmaxf(tm, __shfl_xor(tm, 1));
      tm = fmaxf(tm, __shfl_xor(tm, 2));
      tm = fmaxf(tm, __shfl_xor(tm, 4));
      tm = fmaxf(tm, __shfl_xor(tm, 8));
      tmv[j] = tm;
      grow |= (tm > mrun[j] + 8.0f) ? 1 : 0;
    }
    if (__any(grow)) {                          // rare: only on real max growth
      float al[4];
#pragma unroll
      for (int j = 0; j < 4; ++j) {
        float mn = fmaxf(mrun[j], tmv[j]);
        al[j] = __expf(mrun[j] - mn);
        mrun[j] = mn;
        lrun[j] *= al[j];
      }
#pragma unroll
      for (int n = 0; n < 32; ++n) {
#pragma unroll
        for (int j = 0; j < 4; ++j) acc[n][j] *= al[j];
      }
    }
#pragma unroll
    for (int j = 0; j < 4; ++j) {
      float p0 = __expf(s0[j] - mrun[j]);       // bounded by e^8
      float p1 = __expf(s1[j] - mrun[j]);
      s0[j] = p0; s1[j] = p1;
      float rs = p0 + p1;
      rs += __shfl_xor(rs, 1);
      rs += __shfl_xor(rs, 2);
      rs += __shfl_xor(rs, 4);
      rs += __shfl_xor(rs, 8);
      lrun[j] += rs;
    }

    // ---- P -> private LDS bounce (stride 80, wave-private, no barrier needed) ----
#pragma unroll
    for (int j = 0; j < 4; ++j) {
      int q = 4 * g + j;
      int swzP = ((q ^ (q >> 2)) & 3) << 4;
      *(unsigned short*)(pbase + q * 80 + ((2 * lq) ^ swzP))      = f2bf(s0[j]);
      *(unsigned short*)(pbase + q * 80 + ((32 + 2 * lq) ^ swzP)) = f2bf(s1[j]);
    }
    // ---- O += P V ----
    bf16x8 pa = *(const bf16x8*)(pbase + lq * 80 + ((16 * g) ^ swzA));
#pragma unroll
    for (int n = 0; n < 32; ++n) {
      int d = 16 * n + lq;
      int swzV = ((d ^ (d >> 2)) & 3) << 4;
      bf16x8 vb8 = *(const bf16x8*)(vb + d * 64 + ((16 * g) ^ swzV));
      acc[n] = __builtin_amdgcn_mfma_f32_16x16x32_bf16(pa, vb8, acc[n], 0, 0, 0);
    }

    asm volatile("s_waitcnt vmcnt(0)" ::: "memory");  // next tile staged
    __syncthreads();                                   // + all reads of cur done
  }

  // ---- epilogue: out = acc / l * gate ----
  float rl[4];
#pragma unroll
  for (int j = 0; j < 4; ++j) rl[j] = 1.0f / lrun[j];
#pragma unroll
  for (int n = 0; n < 32; ++n) {
    int d = 16 * n + lq;
    float gg = g8[n >> 2];
    float* op = out + ((long)(bh * T_SEQ + qw + 4 * g) << 9) + d;
#pragma unroll
    for (int j = 0; j < 4; ++j) op[(long)j << 9] = acc[n][j] * rl[j] * gg;
  }
}

extern "C" void kernel_launch(void* const* d_in, const int* in_sizes, int n_in,
                              void* d_out, int out_size, void* d_ws, size_t ws_size,
                              hipStream_t stream) {
  (void)in_sizes; (void)n_in; (void)out_size; (void)ws_size;
  const float* Q     = (const float*)d_in[0];
  const float* K     = (const float*)d_in[1];
  const float* V     = (const float*)d_in[2];
  const float* route = (const float*)d_in[3];
  const int*   mask  = (const int*)d_in[5];
  float* out = (float*)d_out;
  unsigned short* kws = (unsigned short*)d_ws;
  unsigned short* vtw = (unsigned short*)((char*)d_ws + 33554432);
  prep_k  <<<8192, 256, 0, stream>>>(K, kws);
  prep_vt <<<4096, 256, 0, stream>>>(V, vtw);
  attn_main<<<256, 512, 0, stream>>>(Q, route, mask, kws, vtw, out);
}